// Round 11
// baseline (570.928 us; speedup 1.0000x reference)
//
#include <hip/hip_runtime.h>
#include <math.h>

// CRF forward partition scan. B=512, S=1024, T=48.
// One 64-lane wave per batch element. Lane j owns tag j (lanes 48..63 clamp).
//
// R10 post-mortem (first matched prediction): pk-math + SGPR mask cut issue
// volume, 526->439us. Remaining stall ~700 cyc/iter = LDS pipe occupancy
// (12 distributed T-reads + 24 broadcasts, x2 waves/CU) + 2 serial LDS
// round trips. R11 removes the distributed T-reads: T joins E in registers
// (24+24 v2 pairs, ~130 VGPRs, fine at launch_bounds(64,1)).
// Remat-proofing WITHOUT inline asm (R6/R7's only untested novelty before
// two container failures): a prep kernel materializes transposed T and
// E=exp(T) into d_ws; crf_fwd loads them through a VOLATILE pointer.
// Volatile loads can't be duplicated/sunk/remat'd -> values must stay
// resident (or visibly spill -> WRITE_SIZE would balloon; falsifier).

constexpr int kB  = 512;
constexpr int kS  = 1024;
constexpr int kT  = 48;

typedef float v2 __attribute__((ext_vector_type(2)));
struct V2P { v2 lo, hi; };

#define REP12(X) X(0) X(1) X(2) X(3) X(4) X(5) X(6) X(7) X(8) X(9) X(10) X(11)

// X(k, i0, i1): pair k covers transition rows i0=2k, i1=2k+1
#define REP24(X) \
  X(0,0,1)    X(1,2,3)    X(2,4,5)    X(3,6,7) \
  X(4,8,9)    X(5,10,11)  X(6,12,13)  X(7,14,15) \
  X(8,16,17)  X(9,18,19)  X(10,20,21) X(11,22,23) \
  X(12,24,25) X(13,26,27) X(14,28,29) X(15,30,31) \
  X(16,32,33) X(17,34,35) X(18,36,37) X(19,38,39) \
  X(20,40,41) X(21,42,43) X(22,44,45) X(23,46,47)

// X(q, evA, evB, a, b): quad q (rows 4q..4q+3), pair ids 2q/2q+1, acc ids
#define REPQ(X) \
  X(0,0,1,0,3)    X(1,2,3,1,2)    X(2,4,5,2,1)    X(3,6,7,3,0) \
  X(4,8,9,0,3)    X(5,10,11,1,2)  X(6,12,13,2,1)  X(7,14,15,3,0) \
  X(8,16,17,0,3)  X(9,18,19,1,2)  X(10,20,21,2,1) X(11,22,23,3,0)

#define DECL_TEV(k,i0,i1)  v2 TV##k, EV##k;
// volatile loads: executed exactly once, un-rematerializable.
#define INIT_TEV(k,i0,i1)  TV##k = (v2){tp[i0], tp[i1]}; \
                           EV##k = (v2){ep[i0], ep[i1]};

#define LOADP(q)  const float4 P##q  = p4[q];
#define LOADQ(q)  const float4 Q##q  = q4[q];

// pass 1: mv[a] = pk_max(mv[a], TV[evA] + p.lo); mv[b] likewise with hi
#define PASS1(q,evA,evB,a,b) { \
    const V2P p_ = __builtin_bit_cast(V2P, P##q);  \
    mv##a = __builtin_elementwise_max(mv##a, TV##evA + p_.lo); \
    mv##b = __builtin_elementwise_max(mv##b, TV##evB + p_.hi); }

// pass 2: sv[a] += EV[evA] * q.lo; sv[b] += EV[evB] * q.hi   (pk_fma)
#define PASS2(q,evA,evB,a,b) { \
    const V2P q_ = __builtin_bit_cast(V2P, Q##q); \
    sv##a = __builtin_elementwise_fma(EV##evA, q_.lo, sv##a); \
    sv##b = __builtin_elementwise_fma(EV##evB, q_.hi, sv##b); }

// Single-wave workgroup: LDS pipe is in-order per wave; cross-lane RAW
// through LDS needs only a compiler scheduling fence, not s_barrier.
__device__ __forceinline__ void wave_fence() {
    __builtin_amdgcn_wave_barrier();
}

// Materialize Tt[j][i] = trans[i][j] and Et[j][i] = exp(trans[i][j]) in ws.
__global__ __launch_bounds__(256) void prep(
    const float* __restrict__ trans, float* __restrict__ ws)
{
    const int idx = blockIdx.x * 256 + threadIdx.x;
    if (idx < kT * kT) {
        const int i = idx / kT, j = idx % kT;
        const float t = trans[i * kT + j];
        ws[j * kT + i]           = t;          // Tt
        ws[kT * kT + j * kT + i] = __expf(t);  // Et
    }
}

__global__ __launch_bounds__(64, 1) void crf_fwd(
    const float* __restrict__ feats,   // [B, S, T] fp32
    const int*   __restrict__ mask,    // [B, S] int32 (bool)
    const float* __restrict__ ws,      // [2*48*48]: Tt then Et
    float*       __restrict__ out)     // [1 + B]; we write out[1+b]
{
    const int b    = blockIdx.x;
    const int lane = threadIdx.x;
    const int j    = (lane < kT) ? lane : (kT - 1);  // clamp idle lanes

    __shared__ alignas(16) float p_sh[64];   // part_i
    __shared__ alignas(16) float ea_sh[64];  // exp(part_i - e_i - M_i)
    const float4* p4 = (const float4*)p_sh;
    const float4* q4 = (const float4*)ea_sh;

    // T and E columns as 24+24 packed float2 in registers, loaded through a
    // volatile pointer so they cannot be rematerialized inside the loop.
    const volatile float* tp = ws + (size_t)j * kT;
    const volatile float* ep = ws + (size_t)kT * kT + (size_t)j * kT;
    REP24(DECL_TEV)
    REP24(INIT_TEV)

    const float* fb = feats + (size_t)b * kS * kT + j;  // lane-offset base
    const int*   mb = mask  + (size_t)b * kS;

    // part0 = emit[0] + transition[T-2, :]  (row 46 = TV23.x)
    float part = fb[0] + TV23.x;
    p_sh[lane] = part;
    wave_fence();   // order p_sh init before loop reads

    // Depth-4 register-rotated prefetch of emission (mask is SALU now).
    float e0v = fb[(size_t)1 * kT], e1v = fb[(size_t)2 * kT],
          e2v = fb[(size_t)3 * kT], e3v = fb[(size_t)4 * kT];
    int mreg = mb[lane];   // mask words for steps 0..63 (coalesced)

    for (int blk = 0; blk < 16; ++blk) {
        // Uniform 64-step mask bitmask in an SGPR pair; per-step gate is
        // s_and/s_lshr + branch -- zero memory, zero VALU.
        unsigned long long bits = __ballot(mreg != 0);
        if (blk < 15) mreg = mb[(blk + 1) * 64 + lane];  // next block's word
        int t = blk * 64;
        const int tend = t + 64;
        if (blk == 0) { bits >>= 1; t = 1; }  // scan starts at step 1

        for (; t < tend; ++t) {
            const float e = e0v;
            e0v = e1v; e1v = e2v; e2v = e3v;
            const int tn = (t + 4 < kS) ? (t + 4) : (kS - 1);
            e3v = fb[(size_t)tn * kT];
            const bool mk = bits & 1ull;
            bits >>= 1;

            if (mk) {  // wave-uniform branch: skip masked-out steps
                const float pe = part - e;  // off the M-critical path

                // pass 1: M_j = max_i (T[i,j] + part_i); T from registers,
                // p from 12 broadcast float4 LDS reads.
                REP12(LOADP)
                v2 mv0 = {-INFINITY, -INFINITY};
                v2 mv1 = mv0, mv2 = mv0, mv3 = mv0;
                REPQ(PASS1)
                mv0 = __builtin_elementwise_max(mv0, mv1);
                mv2 = __builtin_elementwise_max(mv2, mv3);
                mv0 = __builtin_elementwise_max(mv0, mv2);
                const float M = fmaxf(mv0.x, mv0.y);

                // lane i publishes exp(part_i - e_i - M_i)
                const float ea = __expf(pe - M);
                wave_fence();          // p_sh reads precede ea_sh write
                ea_sh[lane] = ea;
                wave_fence();          // ea_sh write precedes LOADQ reads

                // pass 2: S_j = sum_i exp(T[i,j]) * ea_i   (pk_fma chain)
                REP12(LOADQ)
                v2 sv0 = {0.f, 0.f};
                v2 sv1 = sv0, sv2 = sv0, sv3 = sv0;
                REPQ(PASS2)
                sv0 = sv0 + sv1;
                sv2 = sv2 + sv3;
                sv0 = sv0 + sv2;
                const float Ssum = sv0.x + sv0.y;

                part = 2.0f * e + M + __logf(Ssum);
                wave_fence();          // LOADQ reads precede p_sh overwrite
                p_sh[lane] = part;
                wave_fence();          // p_sh write precedes next LOADP
            }
        }
    }

    // Final transition-only step; only end_value[:, T-1] is stored.
    {
        REP12(LOADP)
        v2 mv0 = {-INFINITY, -INFINITY};
        v2 mv1 = mv0, mv2 = mv0, mv3 = mv0;
        REPQ(PASS1)
        mv0 = __builtin_elementwise_max(mv0, mv1);
        mv2 = __builtin_elementwise_max(mv2, mv3);
        mv0 = __builtin_elementwise_max(mv0, mv2);
        const float M = fmaxf(mv0.x, mv0.y);
        const float ea = __expf(part - M);   // no emission in final step
        wave_fence();
        ea_sh[lane] = ea;
        wave_fence();

        REP12(LOADQ)
        v2 sv0 = {0.f, 0.f};
        v2 sv1 = sv0, sv2 = sv0, sv3 = sv0;
        REPQ(PASS2)
        sv0 = sv0 + sv1;
        sv2 = sv2 + sv3;
        sv0 = sv0 + sv2;
        const float Ssum = sv0.x + sv0.y;
        const float val = M + __logf(Ssum);
        if (lane == kT - 1) out[1 + b] = val;  // score[b] = end_value[b,-1]
    }
}

// out[0] = sum(score). Single wave; no barriers needed.
__global__ __launch_bounds__(64) void sum_scores(
    const float* __restrict__ sc, float* __restrict__ out)
{
    float s = 0.f;
    for (int i = (int)threadIdx.x; i < kB; i += 64) s += sc[i];
#pragma unroll
    for (int off = 32; off > 0; off >>= 1) s += __shfl_down(s, off);
    if (threadIdx.x == 0) out[0] = s;
}

extern "C" void kernel_launch(void* const* d_in, const int* in_sizes, int n_in,
                              void* d_out, int out_size, void* d_ws, size_t ws_size,
                              hipStream_t stream) {
    const float* feats = (const float*)d_in[0];
    const int*   mask  = (const int*)d_in[1];
    const float* trans = (const float*)d_in[2];
    float*       out   = (float*)d_out;
    float*       ws    = (float*)d_ws;   // 2*48*48 floats = 18.4 KB

    prep<<<dim3((kT * kT + 255) / 256), dim3(256), 0, stream>>>(trans, ws);
    crf_fwd<<<dim3(kB), dim3(64), 0, stream>>>(feats, mask, ws, out);
    sum_scores<<<dim3(1), dim3(64), 0, stream>>>(out + 1, out);
}